// Round 9
// baseline (66.397 us; speedup 1.0000x reference)
//
#include <hip/hip_runtime.h>
#include <hip/hip_fp16.h>
#include <math.h>

#define NF   30
#define NP   435          // C(30,2)
#define NPAD 448          // 14 tiles of 32 pairs
#define NT   14
#define DIM  64
#define ATT  32
#define WAS  40           // Wt row stride (fp16): 80B, rows 16B-aligned
#define BPB  4            // one batch element per wave

typedef __attribute__((ext_vector_type(8)))  _Float16 half8v;
typedef __attribute__((ext_vector_type(16))) float    f32x16;

// compile-time pair table: p -> (i | j<<8), padded with (31,31) -> zero rows
struct IJTab { unsigned short v[NPAD]; };
static constexpr IJTab make_ij() {
    IJTab t{};
    int p = 0;
    for (int i = 0; i < NF; ++i)
        for (int j = i + 1; j < NF; ++j)
            t.v[p++] = (unsigned short)(i | (j << 8));
    for (; p < NPAD; ++p) t.v[p] = (unsigned short)(31 | (31 << 8));
    return t;
}
__constant__ IJTab IJ = make_ij();

// BCL ("block-column") layout: element [row][c] lives at [c>>3][row][c&7].
// Row-fragment read (8 consecutive c, fixed row) = one b128 at byte offset
// (c>>3)*512 + row*16: the (c>>3) part is a compile-time ds_read immediate in
// the unrolled k-loop; only row*16 is runtime. Column reads are u16 at
// stride 16B with immediate e*16. Bank group = row&7 (same spread as the R7
// XOR swizzle).
struct __align__(16) WaveCtx {
    _Float16 Eh[8][32][8];        // 4096 B; rows 30,31 zero
    union {
        _Float16 UA[4][32][8];    // 2048 B; upper-tri attention exp (unnorm)
        struct { float pooled[DIM]; float h1[32]; float h2[16]; } mlp;
    };
};                                // 6144 B; block = 4*6144 + 2560 = 27136 B -> 6 blk/CU

__launch_bounds__(256, 6)         // 24 waves/CU target; VGPR cap 85
__global__ void afm_wave_kernel(const int*   __restrict__ x,
                                const float* __restrict__ emb,
                                const float* __restrict__ W,     // [64][32]
                                const float* __restrict__ bb,    // [32]
                                const float* __restrict__ hh,    // [32]
                                const float* __restrict__ d1w,   // [32][64]
                                const float* __restrict__ d1b,   // [32]
                                const float* __restrict__ d2w,   // [16][32]
                                const float* __restrict__ d2b,   // [16]
                                const float* __restrict__ fw,    // [16]
                                const float* __restrict__ fb,    // [1]
                                float* __restrict__ out,
                                int Btot)
{
    __shared__ WaveCtx ctx[BPB];
    __shared__ __align__(16) _Float16 Wt[32][WAS];  // W^T fp16, shared across waves

    const int t    = threadIdx.x;
    const int lane = t & 63;
    const int w    = t >> 6;
    const int col  = lane & 31;
    const int half = lane >> 5;
    const int b    = blockIdx.x * BPB + w;

    WaveCtx& C = ctx[w];

    // ---- phase 0: cooperative W^T stage + per-wave E gather / UA zero ----
    {   // W^T -> Wt fp16 (block-cooperative; ds_write_b128 per thread)
        const int a = t >> 3, kb = (t & 7) * 8;
        half8v w8;
        #pragma unroll
        for (int e = 0; e < 8; ++e) w8[e] = (_Float16)W[(kb + e) * ATT + a];
        *(half8v*)&Wt[a][kb] = w8;
    }
    if (b < Btot) {
        // E gather -> BCL fp16 LDS; rows 30,31 zero
        #pragma unroll
        for (int it = 0; it < 4; ++it) {
            const int s = it * 64 + lane;
            const int row = s >> 3, blk = s & 7;
            half8v v8 = {};
            if (row < NF) {
                const int xr = x[b * NF + row];
                const float4 f0 = *(const float4*)&emb[(long)xr * DIM + blk * 8];
                const float4 f1 = *(const float4*)&emb[(long)xr * DIM + blk * 8 + 4];
                v8[0] = (_Float16)f0.x; v8[1] = (_Float16)f0.y;
                v8[2] = (_Float16)f0.z; v8[3] = (_Float16)f0.w;
                v8[4] = (_Float16)f1.x; v8[5] = (_Float16)f1.y;
                v8[6] = (_Float16)f1.z; v8[7] = (_Float16)f1.w;
            }
            *(half8v*)&C.Eh[blk][row][0] = v8;       // one b128 store
        }
        // zero UA: 2048 B = 128 x float4
        const float4 z = make_float4(0.f, 0.f, 0.f, 0.f);
        ((float4*)C.UA)[lane]      = z;
        ((float4*)C.UA)[lane + 64] = z;
    }
    __syncthreads();                                 // the ONLY barrier (Wt)

    if (b >= Btot) return;

    // A-fragments (W^T) from LDS: one ds_read_b128 each
    half8v wfrag[4];
    #pragma unroll
    for (int ks = 0; ks < 4; ++ks)
        wfrag[ks] = *(const half8v*)&Wt[col][ks * 16 + half * 8];

    // bias/h fragments: C-row r -> a = (r&3) + 8*(r>>2) + 4*half
    float4 b4[4], h4[4];
    #pragma unroll
    for (int q = 0; q < 4; ++q) {
        b4[q] = *(const float4*)&bb[8 * q + 4 * half];
        h4[q] = *(const float4*)&hh[8 * q + 4 * half];
    }

    const _Float16* EhB = &C.Eh[0][0][0] + (half << 8);   // + half*512 B

    // ---- phase 1: 14 tiles; acc init = bias (MFMA C-in); fused exp->UA ----
    float wsum = 0.f;
    #pragma unroll 1
    for (int tile = 0; tile < NT; ++tile) {
        const int p  = tile * 32 + col;
        const int pj = IJ.v[p];
        const int fi = pj & 255, fj = pj >> 8;
        const _Float16* Ei = EhB + (fi << 3);
        const _Float16* Ej = EhB + (fj << 3);
        f32x16 acc;
        #pragma unroll
        for (int q = 0; q < 4; ++q) {
            acc[4 * q + 0] = b4[q].x; acc[4 * q + 1] = b4[q].y;
            acc[4 * q + 2] = b4[q].z; acc[4 * q + 3] = b4[q].w;
        }
        #pragma unroll
        for (int ks = 0; ks < 4; ++ks) {
            const half8v va = *(const half8v*)(Ei + ks * 512);   // imm offset ks*1024B
            const half8v vc = *(const half8v*)(Ej + ks * 512);
            acc = __builtin_amdgcn_mfma_f32_32x32x16_f16(wfrag[ks], va * vc, acc, 0, 0, 0);
        }
        float sv = 0.f;
        #pragma unroll
        for (int q = 0; q < 4; ++q) {
            sv += fmaxf(acc[4 * q + 0], 0.f) * h4[q].x;
            sv += fmaxf(acc[4 * q + 1], 0.f) * h4[q].y;
            sv += fmaxf(acc[4 * q + 2], 0.f) * h4[q].z;
            sv += fmaxf(acc[4 * q + 3], 0.f) * h4[q].w;
        }
        sv += __shfl_xor(sv, 32);
        // |s| <~ 0.2 by construction -> exp without max-subtract (validated R3-R8)
        if (half == 0 && p < NP) {
            const float ex = __expf(sv);
            C.UA[fj >> 3][fi][fj & 7] = (_Float16)ex;    // BCL scatter
            wsum += ex;
        }
    }
    #pragma unroll
    for (int o = 1; o <= 16; o <<= 1) wsum += __shfl_xor(wsum, o);
    const float inv_sum = 1.f / wsum;                // valid on half==0 lanes

    // ---- phase 3: T = UA @ E; pooled[d] = inv_sum * sum_i E[i][d]*T[i][d] ----
    // uaf reads hoisted BEFORE pooled writes (pooled overlays UA).
    const _Float16* UAb = (const _Float16*)C.UA + (half << 8) + (col << 3);
    const half8v uaf0 = *(const half8v*)(UAb);           // imm 0
    const half8v uaf1 = *(const half8v*)(UAb + 512);     // imm 1024B
    #pragma unroll
    for (int dh = 0; dh < 2; ++dh) {
        const int d = col + 32 * dh;
        const _Float16* Bd  = &C.Eh[0][0][0] + ((d >> 3) << 8) + (d & 7);
        const _Float16* BdB = Bd + (half << 6);          // B-frag rows (half*8)
        f32x16 tacc = {};
        #pragma unroll
        for (int ks = 0; ks < 2; ++ks) {
            half8v eb;
            #pragma unroll
            for (int e = 0; e < 8; ++e) eb[e] = BdB[ks * 128 + e * 8];  // u16, imm offs
            tacc = __builtin_amdgcn_mfma_f32_32x32x16_f16(ks ? uaf1 : uaf0, eb, tacc, 0, 0, 0);
        }
        const _Float16* BdC = Bd + (half << 5);          // C-layout rows (4*half)
        float sv = 0.f;
        #pragma unroll
        for (int q = 0; q < 4; ++q) {
            #pragma unroll
            for (int s = 0; s < 4; ++s)
                sv += (float)BdC[(q << 6) + (s << 3)] * tacc[4 * q + s];
        }
        sv += __shfl_xor(sv, 32);
        if (half == 0) C.mlp.pooled[d] = sv * inv_sum;
    }

    // ---- phase 4: MLP 64->32->16->1 in-wave (within-wave LDS ordering) ----
    {   // d1: 32 outputs x 2 lanes, float4 reads
        const int o = lane >> 1, part = lane & 1;
        const float4* wr4 = (const float4*)&d1w[o * DIM + part * 32];
        const float4* pp4 = (const float4*)&C.mlp.pooled[part * 32];
        float a1 = 0.f;
        #pragma unroll
        for (int k = 0; k < 8; ++k) {
            const float4 wv = wr4[k], pv = pp4[k];
            a1 = fmaf(pv.x, wv.x, a1);
            a1 = fmaf(pv.y, wv.y, a1);
            a1 = fmaf(pv.z, wv.z, a1);
            a1 = fmaf(pv.w, wv.w, a1);
        }
        a1 += __shfl_xor(a1, 1);
        if (part == 0) C.mlp.h1[o] = fmaxf(a1 + d1b[o], 0.f);
    }
    {   // d2: 16 outputs x 4 lanes
        const int o = lane >> 2, part = lane & 3;
        float a2 = 0.f;
        #pragma unroll
        for (int k = 0; k < 8; ++k)
            a2 = fmaf(C.mlp.h1[part * 8 + k], d2w[o * 32 + part * 8 + k], a2);
        a2 += __shfl_xor(a2, 1);
        a2 += __shfl_xor(a2, 2);
        if (part == 0) C.mlp.h2[o] = fmaxf(a2 + d2b[o], 0.f);
    }
    if (lane < 16) {
        float v = C.mlp.h2[lane] * fw[lane];
        #pragma unroll
        for (int o2 = 1; o2 < 16; o2 <<= 1) v += __shfl_xor(v, o2);
        if (lane == 0) out[b] = 1.f / (1.f + __expf(-(v + fb[0])));
    }
}

extern "C" void kernel_launch(void* const* d_in, const int* in_sizes, int n_in,
                              void* d_out, int out_size, void* d_ws, size_t ws_size,
                              hipStream_t stream) {
    (void)n_in; (void)d_ws; (void)ws_size; (void)out_size;
    const int*   x   = (const int*)  d_in[0];
    const float* emb = (const float*)d_in[1];
    const float* W   = (const float*)d_in[2];
    const float* bbp = (const float*)d_in[3];
    const float* hhp = (const float*)d_in[4];
    const float* d1w = (const float*)d_in[5];
    const float* d1b = (const float*)d_in[6];
    const float* d2w = (const float*)d_in[7];
    const float* d2b = (const float*)d_in[8];
    const float* fw  = (const float*)d_in[9];
    const float* fb  = (const float*)d_in[10];
    float* out = (float*)d_out;

    const int B = in_sizes[0] / NF;
    const int grid = (B + BPB - 1) / BPB;
    afm_wave_kernel<<<grid, 256, 0, stream>>>(x, emb, W, bbp, hhp,
                                              d1w, d1b, d2w, d2b, fw, fb, out, B);
}

// Round 10
// 50.521 us; speedup vs baseline: 1.3142x; 1.3142x over previous
//
#include <hip/hip_runtime.h>
#include <hip/hip_fp16.h>
#include <math.h>

#define NF   30
#define NP   435          // C(30,2)
#define NPAD 448          // 14 tiles of 32 pairs
#define NT   14
#define DIM  64
#define ATT  32
#define WAS  40           // Wt row stride (fp16): 80B, rows 16B-aligned
#define BPB  2            // batch elements per block; TWO waves cooperate per b

typedef __attribute__((ext_vector_type(8)))  _Float16 half8v;
typedef __attribute__((ext_vector_type(16))) float    f32x16;

// compile-time pair table: p -> (i | j<<8), padded with (31,31) -> zero rows
struct IJTab { unsigned short v[NPAD]; };
static constexpr IJTab make_ij() {
    IJTab t{};
    int p = 0;
    for (int i = 0; i < NF; ++i)
        for (int j = i + 1; j < NF; ++j)
            t.v[p++] = (unsigned short)(i | (j << 8));
    for (; p < NPAD; ++p) t.v[p] = (unsigned short)(31 | (31 << 8));
    return t;
}
__constant__ IJTab IJ = make_ij();

// XOR-swizzled layouts (proven R7/R8): 16B block index ^= (row&7).
__device__ __forceinline__ int eh_off(int row, int d) {      // Eh logical [32][64]
    return (row << 6) + ((((d >> 3) ^ (row & 7)) << 3) | (d & 7));
}

struct __align__(16) WaveCtx {
    _Float16 Eh[32 * 64];   // 4096 B (rows 30,31 zero)
    _Float16 UA[32 * 32];   // 2048 B upper-tri attention exp (unnormalized)
    float    pooled[DIM];   // 256 B
    float    red[2];        // per-wave wsum partials
    float    h1[32];
    float    h2[16];
};                          // 6600 B -> block: 2*ctx + Wt 2560 = ~15.8 KB -> 10 blk/CU
                            // -> residency HW-capped at 32 waves/CU (was 20)

__launch_bounds__(256, 4)   // VGPR cap 128: NO forced spill (R6/R9 lesson)
__global__ void afm_wave_kernel(const int*   __restrict__ x,
                                const float* __restrict__ emb,
                                const float* __restrict__ W,     // [64][32]
                                const float* __restrict__ bb,    // [32]
                                const float* __restrict__ hh,    // [32]
                                const float* __restrict__ d1w,   // [32][64]
                                const float* __restrict__ d1b,   // [32]
                                const float* __restrict__ d2w,   // [16][32]
                                const float* __restrict__ d2b,   // [16]
                                const float* __restrict__ fw,    // [16]
                                const float* __restrict__ fb,    // [1]
                                float* __restrict__ out,
                                int Btot)
{
    __shared__ WaveCtx ctx[BPB];
    __shared__ __align__(16) _Float16 Wt[32][WAS];  // W^T fp16, shared across waves

    const int t    = threadIdx.x;
    const int lane = t & 63;
    const int wv   = t >> 6;         // 0..3
    const int pr   = wv >> 1;        // pair id: which b of the block
    const int h    = wv & 1;         // role within the pair
    const int col  = lane & 31;
    const int half = lane >> 5;
    const int b    = blockIdx.x * BPB + pr;
    const int bc   = (b < Btot) ? b : (Btot - 1);   // clamped for loads

    WaveCtx& C = ctx[pr];

    // ---- phase 0: cooperative W^T stage + split E gather / UA zero ----
    {   // W^T -> Wt fp16 (all 256 threads)
        const int a = t >> 3, kb = (t & 7) * 8;
        half8v w8;
        #pragma unroll
        for (int e = 0; e < 8; ++e) w8[e] = (_Float16)W[(kb + e) * ATT + a];
        *(half8v*)&Wt[a][kb] = w8;
    }
    // E gather: wave h loads rows [16h, 16h+16)
    #pragma unroll
    for (int it = 0; it < 2; ++it) {
        const int s = h * 128 + it * 64 + lane;
        const int row = s >> 3, blk = s & 7;
        half8v v8 = {};
        if (row < NF) {
            const int xr = x[bc * NF + row];
            const float4 f0 = *(const float4*)&emb[(long)xr * DIM + blk * 8];
            const float4 f1 = *(const float4*)&emb[(long)xr * DIM + blk * 8 + 4];
            v8[0] = (_Float16)f0.x; v8[1] = (_Float16)f0.y;
            v8[2] = (_Float16)f0.z; v8[3] = (_Float16)f0.w;
            v8[4] = (_Float16)f1.x; v8[5] = (_Float16)f1.y;
            v8[6] = (_Float16)f1.z; v8[7] = (_Float16)f1.w;
        }
        *(half8v*)&C.Eh[(row << 6) + ((blk ^ (row & 7)) << 3)] = v8;  // b128 store
    }
    // zero this wave's half of UA (2048 B total = 128 x float4)
    {
        const float4 z = make_float4(0.f, 0.f, 0.f, 0.f);
        ((float4*)C.UA)[h * 64 + lane] = z;
    }
    __syncthreads();                                 // B1: Wt + Eh + UA ready

    // A-fragments (W^T) from LDS: one ds_read_b128 each
    half8v wfrag[4];
    #pragma unroll
    for (int ks = 0; ks < 4; ++ks)
        wfrag[ks] = *(const half8v*)&Wt[col][ks * 16 + half * 8];

    // bias/h fragments: C-row r -> a = (r&3) + 8*(r>>2) + 4*half
    float4 b4[4], h4[4];
    #pragma unroll
    for (int q = 0; q < 4; ++q) {
        b4[q] = *(const float4*)&bb[8 * q + 4 * half];
        h4[q] = *(const float4*)&hh[8 * q + 4 * half];
    }

    // ---- phase 1: wave h runs tiles {h, h+2, ..., h+12} (7 of 14) ----
    float wsum = 0.f;
    #pragma unroll 1
    for (int tt = 0; tt < 7; ++tt) {
        const int tile = 2 * tt + h;
        const int p  = tile * 32 + col;
        const int pj = IJ.v[p];
        const int fi = pj & 255, fj = pj >> 8;
        const _Float16* Ei = &C.Eh[fi << 6];
        const _Float16* Ej = &C.Eh[fj << 6];
        const int si = fi & 7, sj = fj & 7;
        f32x16 acc = {};
        #pragma unroll
        for (int ks = 0; ks < 4; ++ks) {
            const int blk = 2 * ks + half;                           // d0 >> 3
            const half8v va = *(const half8v*)&Ei[(blk ^ si) << 3];  // ds_read_b128
            const half8v vc = *(const half8v*)&Ej[(blk ^ sj) << 3];  // ds_read_b128
            acc = __builtin_amdgcn_mfma_f32_32x32x16_f16(wfrag[ks], va * vc, acc, 0, 0, 0);
        }
        float sv = 0.f;
        #pragma unroll
        for (int q = 0; q < 4; ++q) {
            sv += fmaxf(acc[4 * q + 0] + b4[q].x, 0.f) * h4[q].x;
            sv += fmaxf(acc[4 * q + 1] + b4[q].y, 0.f) * h4[q].y;
            sv += fmaxf(acc[4 * q + 2] + b4[q].z, 0.f) * h4[q].z;
            sv += fmaxf(acc[4 * q + 3] + b4[q].w, 0.f) * h4[q].w;
        }
        sv += __shfl_xor(sv, 32);
        // |s| <~ 0.2 by construction -> exp without max-subtract (validated R3-R9)
        if (half == 0 && p < NP) {
            const float ex = __expf(sv);
            C.UA[(fi << 5) + ((((fj >> 3) ^ (fi & 7)) << 3) | (fj & 7))] = (_Float16)ex;
            wsum += ex;
        }
    }
    #pragma unroll
    for (int o = 1; o <= 16; o <<= 1) wsum += __shfl_xor(wsum, o);
    if (lane == 0) C.red[h] = wsum;
    __syncthreads();                                 // B2: UA + partials ready
    const float inv_sum = 1.f / (C.red[0] + C.red[1]);

    // ---- phase 3: wave h computes dh = h (32 of 64 pooled dims) ----
    {
        const int d = col + 32 * h;
        half8v uaf[2];
        #pragma unroll
        for (int ks = 0; ks < 2; ++ks)
            uaf[ks] = *(const half8v*)&C.UA[(col << 5) + (((2 * ks + half) ^ (col & 7)) << 3)];
        f32x16 tacc = {};
        #pragma unroll
        for (int ks = 0; ks < 2; ++ks) {
            const int j0 = ks * 16 + half * 8;
            half8v eb;
            #pragma unroll
            for (int e = 0; e < 8; ++e) eb[e] = C.Eh[eh_off(j0 + e, d)];  // column read
            tacc = __builtin_amdgcn_mfma_f32_32x32x16_f16(uaf[ks], eb, tacc, 0, 0, 0);
        }
        float sv = 0.f;
        #pragma unroll
        for (int q = 0; q < 4; ++q) {
            const int i0 = 8 * q + 4 * half;
            #pragma unroll
            for (int s = 0; s < 4; ++s)
                sv += (float)C.Eh[eh_off(i0 + s, d)] * tacc[4 * q + s];
        }
        sv += __shfl_xor(sv, 32);
        if (half == 0) C.pooled[d] = sv * inv_sum;
    }
    __syncthreads();                                 // B3: pooled complete

    // ---- phase 4: MLP 64->32->16->1, wave h==0 of each pair ----
    if (h == 0) {
        {   // d1: 32 outputs x 2 lanes, float4 reads
            const int o = lane >> 1, part = lane & 1;
            const float4* wr4 = (const float4*)&d1w[o * DIM + part * 32];
            const float4* pp4 = (const float4*)&C.pooled[part * 32];
            float a1 = 0.f;
            #pragma unroll
            for (int k = 0; k < 8; ++k) {
                const float4 wvv = wr4[k], pv = pp4[k];
                a1 = fmaf(pv.x, wvv.x, a1);
                a1 = fmaf(pv.y, wvv.y, a1);
                a1 = fmaf(pv.z, wvv.z, a1);
                a1 = fmaf(pv.w, wvv.w, a1);
            }
            a1 += __shfl_xor(a1, 1);
            if (part == 0) C.h1[o] = fmaxf(a1 + d1b[o], 0.f);
        }
        {   // d2: 16 outputs x 4 lanes
            const int o = lane >> 2, part = lane & 3;
            float a2 = 0.f;
            #pragma unroll
            for (int k = 0; k < 8; ++k)
                a2 = fmaf(C.h1[part * 8 + k], d2w[o * 32 + part * 8 + k], a2);
            a2 += __shfl_xor(a2, 1);
            a2 += __shfl_xor(a2, 2);
            if (part == 0) C.h2[o] = fmaxf(a2 + d2b[o], 0.f);
        }
        if (lane < 16) {
            float v = C.h2[lane] * fw[lane];
            #pragma unroll
            for (int o2 = 1; o2 < 16; o2 <<= 1) v += __shfl_xor(v, o2);
            if (lane == 0 && b < Btot)
                out[b] = 1.f / (1.f + __expf(-(v + fb[0])));
        }
    }
}

extern "C" void kernel_launch(void* const* d_in, const int* in_sizes, int n_in,
                              void* d_out, int out_size, void* d_ws, size_t ws_size,
                              hipStream_t stream) {
    (void)n_in; (void)d_ws; (void)ws_size; (void)out_size;
    const int*   x   = (const int*)  d_in[0];
    const float* emb = (const float*)d_in[1];
    const float* W   = (const float*)d_in[2];
    const float* bbp = (const float*)d_in[3];
    const float* hhp = (const float*)d_in[4];
    const float* d1w = (const float*)d_in[5];
    const float* d1b = (const float*)d_in[6];
    const float* d2w = (const float*)d_in[7];
    const float* d2b = (const float*)d_in[8];
    const float* fw  = (const float*)d_in[9];
    const float* fb  = (const float*)d_in[10];
    float* out = (float*)d_out;

    const int B = in_sizes[0] / NF;
    const int grid = (B + BPB - 1) / BPB;
    afm_wave_kernel<<<grid, 256, 0, stream>>>(x, emb, W, bbp, hhp,
                                              d1w, d1b, d2w, d2b, fw, fb, out, B);
}